// Round 3
// baseline (261.026 us; speedup 1.0000x reference)
//
#include <hip/hip_runtime.h>
#include <hip/hip_bf16.h>

// SparseAttentionHead on MI355X.
// out[i,c] = elu( sum_j P[i,j] * F[j,c] / Z[i] ),
//   P[i,j] = exp( adj[i,j] * lrelu(a1[i]+a2[j]) )   (adj in {0,1}; exp(0)=1 for adj=0)
//   Z[i]   = sum_j P[i,j]
// No max-subtraction: a1+a2 ~ N(0,2), max ~9 -> exp safe in fp32.
//
// v3: occupancy. BM=16 rows/block, 8 waves (512 thr), wave w owns K-chunk
// [w*1024, w*1024+1024) -> 32 steps of 32. grid 512 -> 2 blocks/CU,
// 16 waves/CU (needs VGPR<=128 via launch_bounds(512,4)). Hot loop has no
// barriers; A-frags built in registers from adj; 2-deep adj/a2 prefetch.
// Cross-wave reduce via exactly 64KB LDS at the end (z staged first).

typedef short bf16x8 __attribute__((ext_vector_type(8)));
typedef float f32x4 __attribute__((ext_vector_type(4)));

static __device__ __forceinline__ short f2bf(float f) {
  union { float f; unsigned u; } v; v.f = f;
  unsigned r = v.u + 0x7fffu + ((v.u >> 16) & 1u);
  return (short)(r >> 16);
}

// K1: seq_fts = W1 @ x (fp32), store FT[c][n] = bf16(seq_fts), accumulate a1/a2.
__global__ __launch_bounds__(256) void k1_seqfts(
    const float* __restrict__ x, const float* __restrict__ W1,
    const float* __restrict__ wf1, const float* __restrict__ wf2,
    short* __restrict__ FT, float* __restrict__ a1, float* __restrict__ a2) {
  const int cb = blockIdx.x & 7;
  const int nb = blockIdx.x >> 3;
  const int n = nb * 256 + threadIdx.x;
  float acc[16];
#pragma unroll
  for (int i = 0; i < 16; ++i) acc[i] = 0.f;
  const float* wrow = W1 + cb * 16 * 128;
#pragma unroll 4
  for (int c = 0; c < 128; ++c) {
    float xv = x[c * 8192 + n];
#pragma unroll
    for (int cc = 0; cc < 16; ++cc) acc[cc] = fmaf(wrow[cc * 128 + c], xv, acc[cc]);
  }
  float p1 = 0.f, p2 = 0.f;
#pragma unroll
  for (int cc = 0; cc < 16; ++cc) {
    int co = cb * 16 + cc;
    FT[co * 8192 + n] = f2bf(acc[cc]);
    p1 = fmaf(wf1[co], acc[cc], p1);
    p2 = fmaf(wf2[co], acc[cc], p2);
  }
  atomicAdd(&a1[n], p1);
  atomicAdd(&a2[n], p2);
}

__global__ __launch_bounds__(512, 4) void k2_attn(
    const float* __restrict__ adj, const short* __restrict__ FT,
    const float* __restrict__ a1, const float* __restrict__ a2,
    const float* __restrict__ b1p, const float* __restrict__ b2p,
    float* __restrict__ out) {
  __shared__ float part[8 * 16 * 128];   // exactly 64 KB -> 2 blocks/CU
  const int t = threadIdx.x;
  const int l = t & 63;
  const int w = t >> 6;        // wave 0..7: K-chunk base w*1024
  const int r = l & 15;        // A row / B col within 16
  const int kg = l >> 4;       // k-subgroup: 8 elems at 8*kg
  const int i0 = blockIdx.x * 16;
  const float af = a1[i0 + r] + b1p[0] + b2p[0];

  const int kb = w * 1024 + kg * 8;
  const float* adjp = adj + (size_t)(i0 + r) * 8192 + kb;
  const float* a2p  = a2 + kb;
  const short* ftr  = FT + (size_t)r * 8192 + kb;   // + cb*131072 + ko per frag

  f32x4 acc[8];
#pragma unroll
  for (int cb = 0; cb < 8; ++cb) acc[cb] = f32x4{0.f, 0.f, 0.f, 0.f};
  float zacc = 0.f;

  auto EXP8 = [&](f32x4 av0, f32x4 av1, f32x4 q0, f32x4 q1) -> bf16x8 {
    bf16x8 afr;
#pragma unroll
    for (int j = 0; j < 4; ++j) {
      float tt = af + q0[j];
      float lr = fmaxf(tt, 0.01f * tt);
      float p = __expf(av0[j] * lr);
      zacc += p;
      afr[j] = f2bf(p);
    }
#pragma unroll
    for (int j = 0; j < 4; ++j) {
      float tt = af + q1[j];
      float lr = fmaxf(tt, 0.01f * tt);
      float p = __expf(av1[j] * lr);
      zacc += p;
      afr[4 + j] = f2bf(p);
    }
    return afr;
  };

  // 2-deep named prefetch: E = step s, O = step s+1 (step stride = 32 floats).
  f32x4 avE0 = *(const f32x4*)(adjp);
  f32x4 avE1 = *(const f32x4*)(adjp + 4);
  f32x4 qE0  = *(const f32x4*)(a2p);
  f32x4 qE1  = *(const f32x4*)(a2p + 4);
  f32x4 avO0 = *(const f32x4*)(adjp + 32);
  f32x4 avO1 = *(const f32x4*)(adjp + 36);
  f32x4 qO0  = *(const f32x4*)(a2p + 32);
  f32x4 qO1  = *(const f32x4*)(a2p + 36);

  for (int s = 0; s < 32; s += 2) {
    {
      const int ko = s * 32;
      bf16x8 b0 = *(const bf16x8*)(ftr + 0 * 131072 + ko);
      bf16x8 b1 = *(const bf16x8*)(ftr + 1 * 131072 + ko);
      bf16x8 b2 = *(const bf16x8*)(ftr + 2 * 131072 + ko);
      bf16x8 b3 = *(const bf16x8*)(ftr + 3 * 131072 + ko);
      bf16x8 b4 = *(const bf16x8*)(ftr + 4 * 131072 + ko);
      bf16x8 b5 = *(const bf16x8*)(ftr + 5 * 131072 + ko);
      bf16x8 b6 = *(const bf16x8*)(ftr + 6 * 131072 + ko);
      bf16x8 b7 = *(const bf16x8*)(ftr + 7 * 131072 + ko);
      bf16x8 afr = EXP8(avE0, avE1, qE0, qE1);
      if (s + 2 < 32) {           // refill E <- s+2 (issues under MFMAs)
        avE0 = *(const f32x4*)(adjp + (s + 2) * 32);
        avE1 = *(const f32x4*)(adjp + (s + 2) * 32 + 4);
        qE0  = *(const f32x4*)(a2p + (s + 2) * 32);
        qE1  = *(const f32x4*)(a2p + (s + 2) * 32 + 4);
      }
      acc[0] = __builtin_amdgcn_mfma_f32_16x16x32_bf16(afr, b0, acc[0], 0, 0, 0);
      acc[1] = __builtin_amdgcn_mfma_f32_16x16x32_bf16(afr, b1, acc[1], 0, 0, 0);
      acc[2] = __builtin_amdgcn_mfma_f32_16x16x32_bf16(afr, b2, acc[2], 0, 0, 0);
      acc[3] = __builtin_amdgcn_mfma_f32_16x16x32_bf16(afr, b3, acc[3], 0, 0, 0);
      acc[4] = __builtin_amdgcn_mfma_f32_16x16x32_bf16(afr, b4, acc[4], 0, 0, 0);
      acc[5] = __builtin_amdgcn_mfma_f32_16x16x32_bf16(afr, b5, acc[5], 0, 0, 0);
      acc[6] = __builtin_amdgcn_mfma_f32_16x16x32_bf16(afr, b6, acc[6], 0, 0, 0);
      acc[7] = __builtin_amdgcn_mfma_f32_16x16x32_bf16(afr, b7, acc[7], 0, 0, 0);
    }
    {
      const int ko = (s + 1) * 32;
      bf16x8 b0 = *(const bf16x8*)(ftr + 0 * 131072 + ko);
      bf16x8 b1 = *(const bf16x8*)(ftr + 1 * 131072 + ko);
      bf16x8 b2 = *(const bf16x8*)(ftr + 2 * 131072 + ko);
      bf16x8 b3 = *(const bf16x8*)(ftr + 3 * 131072 + ko);
      bf16x8 b4 = *(const bf16x8*)(ftr + 4 * 131072 + ko);
      bf16x8 b5 = *(const bf16x8*)(ftr + 5 * 131072 + ko);
      bf16x8 b6 = *(const bf16x8*)(ftr + 6 * 131072 + ko);
      bf16x8 b7 = *(const bf16x8*)(ftr + 7 * 131072 + ko);
      bf16x8 afr = EXP8(avO0, avO1, qO0, qO1);
      if (s + 3 < 32) {           // refill O <- s+3
        avO0 = *(const f32x4*)(adjp + (s + 3) * 32);
        avO1 = *(const f32x4*)(adjp + (s + 3) * 32 + 4);
        qO0  = *(const f32x4*)(a2p + (s + 3) * 32);
        qO1  = *(const f32x4*)(a2p + (s + 3) * 32 + 4);
      }
      acc[0] = __builtin_amdgcn_mfma_f32_16x16x32_bf16(afr, b0, acc[0], 0, 0, 0);
      acc[1] = __builtin_amdgcn_mfma_f32_16x16x32_bf16(afr, b1, acc[1], 0, 0, 0);
      acc[2] = __builtin_amdgcn_mfma_f32_16x16x32_bf16(afr, b2, acc[2], 0, 0, 0);
      acc[3] = __builtin_amdgcn_mfma_f32_16x16x32_bf16(afr, b3, acc[3], 0, 0, 0);
      acc[4] = __builtin_amdgcn_mfma_f32_16x16x32_bf16(afr, b4, acc[4], 0, 0, 0);
      acc[5] = __builtin_amdgcn_mfma_f32_16x16x32_bf16(afr, b5, acc[5], 0, 0, 0);
      acc[6] = __builtin_amdgcn_mfma_f32_16x16x32_bf16(afr, b6, acc[6], 0, 0, 0);
      acc[7] = __builtin_amdgcn_mfma_f32_16x16x32_bf16(afr, b7, acc[7], 0, 0, 0);
    }
  }

  // z across kg lanes sharing row r (l, l^16, l^32, l^48).
  zacc += __shfl_xor(zacc, 16);
  zacc += __shfl_xor(zacc, 32);

  // Phase 1: z through LDS (reuse part buffer), grab zs into registers.
  if (kg == 0) part[w * 2048 + r] = zacc;
  __syncthreads();
  const int e0 = t * 4;          // this thread's 4 output elems
  const int rr = e0 >> 7;        // their row (0..15)
  float zs = 0.f;
#pragma unroll
  for (int ww = 0; ww < 8; ++ww) zs += part[ww * 2048 + rr];
  __syncthreads();

  // Phase 2: store partials. C/D layout: col = l&15, row = 4*(l>>4)+q.
  float* pw = part + w * 2048;
#pragma unroll
  for (int cb = 0; cb < 8; ++cb) {
#pragma unroll
    for (int q = 0; q < 4; ++q)
      pw[(4 * kg + q) * 128 + cb * 16 + r] = acc[cb][q];
  }
  __syncthreads();

  // Phase 3: reduce 8 partials, normalize, elu, store (f32x4 per thread).
  f32x4 v = f32x4{0.f, 0.f, 0.f, 0.f};
#pragma unroll
  for (int ww = 0; ww < 8; ++ww) v += *(const f32x4*)(part + ww * 2048 + e0);
  const float inv = 1.0f / zs;
  f32x4 o;
#pragma unroll
  for (int j = 0; j < 4; ++j) {
    float val = v[j] * inv;
    o[j] = val > 0.f ? val : __expf(val) - 1.f;
  }
  *(f32x4*)(out + (size_t)i0 * 128 + e0) = o;
}

extern "C" void kernel_launch(void* const* d_in, const int* in_sizes, int n_in,
                              void* d_out, int out_size, void* d_ws, size_t ws_size,
                              hipStream_t stream) {
  const float* x   = (const float*)d_in[0];
  // d_in[1] = edge_index (unused by the reference computation)
  const float* adj = (const float*)d_in[2];
  const float* W1  = (const float*)d_in[3];
  const float* wf1 = (const float*)d_in[4];
  const float* b1  = (const float*)d_in[5];
  const float* wf2 = (const float*)d_in[6];
  const float* b2  = (const float*)d_in[7];
  float* out = (float*)d_out;

  short* FT = (short*)d_ws;                                    // 128*8192 bf16 = 2MB
  float* a1 = (float*)((char*)d_ws + (size_t)2 * 1024 * 1024); // 8192 f32
  float* a2 = a1 + 8192;                                       // 8192 f32

  hipMemsetAsync(a1, 0, 2 * 8192 * sizeof(float), stream);
  k1_seqfts<<<256, 256, 0, stream>>>(x, W1, wf1, wf2, FT, a1, a2);
  k2_attn<<<512, 512, 0, stream>>>(adj, FT, a1, a2, b1, b2, out);
}

// Round 4
// 104.458 us; speedup vs baseline: 2.4989x; 2.4989x over previous
//
#include <hip/hip_runtime.h>
#include <hip/hip_bf16.h>

// SparseAttentionHead on MI355X — v4: LDS-staged 2-phase pipeline.
// out[i,c] = elu( sum_j P[i,j]*F[j,c] / Z[i] ),
//   P[i,j] = exp( adj[i,j]*lrelu(a1[i]+a2[j]) ), Z[i] = sum_j P[i,j].
// BM=32 rows/block, BK=128. Per step: adj (16KB) -> regs (2 ahead) -> exp ->
// P bf16 -> LDS; FT tile (32KB) -> LDS via global_load_lds w/ T2 XOR-swizzle
// (pre-swizzled global source, swizzled ds_read). 8 waves: 2M x 4N, each
// 16 rows x 32 cols, 8 MFMA/step. __syncthreads() per step = BW governor.

typedef short bf16x8 __attribute__((ext_vector_type(8)));
typedef float f32x4 __attribute__((ext_vector_type(4)));

static __device__ __forceinline__ short f2bf(float f) {
  union { float f; unsigned u; } v; v.f = f;
  unsigned r = v.u + 0x7fffu + ((v.u >> 16) & 1u);
  return (short)(r >> 16);
}

static __device__ __forceinline__ void gld16(const short* g, short* l) {
  __builtin_amdgcn_global_load_lds(
      (const __attribute__((address_space(1))) void*)g,
      (__attribute__((address_space(3))) void*)l, 16, 0, 0);
}

// K1: seq_fts = W1 @ x (fp32), store FT[c][n] = bf16, accumulate a1/a2.
__global__ __launch_bounds__(256) void k1_seqfts(
    const float* __restrict__ x, const float* __restrict__ W1,
    const float* __restrict__ wf1, const float* __restrict__ wf2,
    short* __restrict__ FT, float* __restrict__ a1, float* __restrict__ a2) {
  const int cb = blockIdx.x & 7;
  const int nb = blockIdx.x >> 3;
  const int n = nb * 256 + threadIdx.x;
  float acc[16];
#pragma unroll
  for (int i = 0; i < 16; ++i) acc[i] = 0.f;
  const float* wrow = W1 + cb * 16 * 128;
#pragma unroll 4
  for (int c = 0; c < 128; ++c) {
    float xv = x[c * 8192 + n];
#pragma unroll
    for (int cc = 0; cc < 16; ++cc) acc[cc] = fmaf(wrow[cc * 128 + c], xv, acc[cc]);
  }
  float p1 = 0.f, p2 = 0.f;
#pragma unroll
  for (int cc = 0; cc < 16; ++cc) {
    int co = cb * 16 + cc;
    FT[co * 8192 + n] = f2bf(acc[cc]);
    p1 = fmaf(wf1[co], acc[cc], p1);
    p2 = fmaf(wf2[co], acc[cc], p2);
  }
  atomicAdd(&a1[n], p1);
  atomicAdd(&a2[n], p2);
}

__global__ __launch_bounds__(512, 2) void k2_attn(
    const float* __restrict__ adj, const short* __restrict__ FT,
    const float* __restrict__ a1, const float* __restrict__ a2,
    const float* __restrict__ b1p, const float* __restrict__ b2p,
    float* __restrict__ out) {
  // P: 32 rows x 128 k bf16, row stride 136 shorts (272B = 17*16: aligned,
  //    rows shift 4 banks). Per-buffer 4360 shorts (16B-multiple).
  __shared__ __align__(16) short Pl[2][4360];
  // FT: 128 c-rows x 128 k bf16, row stride 128 shorts, XOR-swizzled storage.
  __shared__ __align__(16) short Ftl[2][16384];
  __shared__ float zl[32];

  const int t = threadIdx.x;
  const int l = t & 63;
  const int w = t >> 6;
  const int r = l & 15;
  const int kg = l >> 4;
  const int i0 = blockIdx.x * 32;

  // ---- P-producer mapping: thread t -> row t>>4, cols (t&15)*8 .. +8 ----
  const int prow = t >> 4;
  const int pcg = t & 15;
  const float af = a1[i0 + prow] + b1p[0] + b2p[0];
  const float* adjp = adj + (size_t)(i0 + prow) * 8192 + pcg * 8;
  const float* a2p = a2 + pcg * 8;

  // ---- FT staging: wave w instr i covers c = i*32 + w*4 + kg, full 128-k row
  //      split 16B/lane; global source pre-swizzled: +8*(r ^ ((w*4+kg)&15)).
  const int swz = 8 * (r ^ ((w * 4 + kg) & 15));
  const short* fsrc0 = FT + (size_t)(0 + w * 4 + kg) * 8192 + swz;
  const short* fsrc1 = FT + (size_t)(32 + w * 4 + kg) * 8192 + swz;
  const short* fsrc2 = FT + (size_t)(64 + w * 4 + kg) * 8192 + swz;
  const short* fsrc3 = FT + (size_t)(96 + w * 4 + kg) * 8192 + swz;

  // ---- MFMA mapping: wave w -> mtile w>>2 (16 rows), ntiles (w&3)*2, +1 ----
  const int mt = w >> 2;
  const int ct0 = (w & 3) * 2;
  const int arow = mt * 16 + r;      // A row in P tile
  const int c0 = ct0 * 16 + r;       // B col (FT row) for ntile 0

  f32x4 acc0 = {0.f, 0.f, 0.f, 0.f};
  f32x4 acc1 = {0.f, 0.f, 0.f, 0.f};
  float zacc = 0.f;

  auto build = [&](int buf, const f32x4& A0, const f32x4& A1,
                   const f32x4& Q0, const f32x4& Q1) {
    bf16x8 pv;
#pragma unroll
    for (int j = 0; j < 4; ++j) {
      float tt = af + Q0[j];
      float lr = fmaxf(tt, 0.01f * tt);
      float p = __expf(A0[j] * lr);
      zacc += p;
      pv[j] = f2bf(p);
    }
#pragma unroll
    for (int j = 0; j < 4; ++j) {
      float tt = af + Q1[j];
      float lr = fmaxf(tt, 0.01f * tt);
      float p = __expf(A1[j] * lr);
      zacc += p;
      pv[4 + j] = f2bf(p);
    }
    *(bf16x8*)&Pl[buf][prow * 136 + pcg * 8] = pv;
  };

  auto compute = [&](int cur) {
    const short* pb = &Pl[cur][arow * 136 + kg * 8];
    const short* fb = &Ftl[cur][0];
#pragma unroll
    for (int kt = 0; kt < 4; ++kt) {
      const int koff = (kg * 8 + kt * 32) ^ (r * 8);
      bf16x8 Af = *(const bf16x8*)(pb + kt * 32);
      bf16x8 B0 = *(const bf16x8*)(fb + c0 * 128 + koff);
      bf16x8 B1 = *(const bf16x8*)(fb + (c0 + 16) * 128 + koff);
      acc0 = __builtin_amdgcn_mfma_f32_16x16x32_bf16(Af, B0, acc0, 0, 0, 0);
      acc1 = __builtin_amdgcn_mfma_f32_16x16x32_bf16(Af, B1, acc1, 0, 0, 0);
    }
  };

  auto body = [&](int s, const f32x4& uA0, const f32x4& uA1,
                  const f32x4& uQ0, const f32x4& uQ1,
                  f32x4& fA0, f32x4& fA1, f32x4& fQ0, f32x4& fQ1) {
    const int cur = s & 1, nxt = cur ^ 1;
    if (s + 1 < 64) {                       // stage FT(s+1) -> Ftl[nxt]
      const int kb1 = (s + 1) * 128;
      short* fb = &Ftl[nxt][w * 512];
      gld16(fsrc0 + kb1, fb);
      gld16(fsrc1 + kb1, fb + 4096);
      gld16(fsrc2 + kb1, fb + 8192);
      gld16(fsrc3 + kb1, fb + 12288);
    }
    if (s + 2 < 64) {                       // issue adj/a2(s+2) -> regs
      const int kb2 = (s + 2) * 128;
      fA0 = *(const f32x4*)(adjp + kb2);
      fA1 = *(const f32x4*)(adjp + kb2 + 4);
      fQ0 = *(const f32x4*)(a2p + kb2);
      fQ1 = *(const f32x4*)(a2p + kb2 + 4);
    }
    if (s + 1 < 64) build(nxt, uA0, uA1, uQ0, uQ1);  // P(s+1) from regs(s-1)
    compute(cur);                           // MFMA step s from LDS
    __syncthreads();                        // drain vmcnt + swap
  };

  // ---- prologue: FT(0) gloads, adj(0) -> tmp regs, adj(1) -> O regs ----
  {
    short* fb = &Ftl[0][w * 512];
    gld16(fsrc0, fb);
    gld16(fsrc1, fb + 4096);
    gld16(fsrc2, fb + 8192);
    gld16(fsrc3, fb + 12288);
  }
  f32x4 tA0 = *(const f32x4*)(adjp);
  f32x4 tA1 = *(const f32x4*)(adjp + 4);
  f32x4 tQ0 = *(const f32x4*)(a2p);
  f32x4 tQ1 = *(const f32x4*)(a2p + 4);
  f32x4 oA0 = *(const f32x4*)(adjp + 128);
  f32x4 oA1 = *(const f32x4*)(adjp + 132);
  f32x4 oQ0 = *(const f32x4*)(a2p + 128);
  f32x4 oQ1 = *(const f32x4*)(a2p + 132);
  f32x4 eA0 = {0, 0, 0, 0}, eA1 = {0, 0, 0, 0}, eQ0 = {0, 0, 0, 0}, eQ1 = {0, 0, 0, 0};
  build(0, tA0, tA1, tQ0, tQ1);             // P(0)
  __syncthreads();                          // P(0)+FT(0) visible, vmcnt drained

  for (int s = 0; s < 64; s += 2) {
    body(s, oA0, oA1, oQ0, oQ1, eA0, eA1, eQ0, eQ1);      // uses adj(s+1)=O
    body(s + 1, eA0, eA1, eQ0, eQ1, oA0, oA1, oQ0, oQ1);  // uses adj(s+2)=E
  }

  // ---- Z: 16 threads per row -> zl[row] ----
  float zr = zacc;
  zr += __shfl_down(zr, 8, 16);
  zr += __shfl_down(zr, 4, 16);
  zr += __shfl_down(zr, 2, 16);
  zr += __shfl_down(zr, 1, 16);
  if (pcg == 0) zl[prow] = zr;
  __syncthreads();

  // ---- epilogue: C/D layout col=l&15, row=4*kg+q ----
#pragma unroll
  for (int q = 0; q < 4; ++q) {
    const int row = mt * 16 + kg * 4 + q;
    const float inv = 1.0f / zl[row];
    float v0 = acc0[q] * inv;
    v0 = v0 > 0.f ? v0 : __expf(v0) - 1.f;
    out[(size_t)(i0 + row) * 128 + c0] = v0;
    float v1 = acc1[q] * inv;
    v1 = v1 > 0.f ? v1 : __expf(v1) - 1.f;
    out[(size_t)(i0 + row) * 128 + c0 + 16] = v1;
  }
}

extern "C" void kernel_launch(void* const* d_in, const int* in_sizes, int n_in,
                              void* d_out, int out_size, void* d_ws, size_t ws_size,
                              hipStream_t stream) {
  const float* x   = (const float*)d_in[0];
  // d_in[1] = edge_index (unused by the reference computation)
  const float* adj = (const float*)d_in[2];
  const float* W1  = (const float*)d_in[3];
  const float* wf1 = (const float*)d_in[4];
  const float* b1  = (const float*)d_in[5];
  const float* wf2 = (const float*)d_in[6];
  const float* b2  = (const float*)d_in[7];
  float* out = (float*)d_out;

  short* FT = (short*)d_ws;                                    // 128*8192 bf16 = 2MB
  float* a1 = (float*)((char*)d_ws + (size_t)2 * 1024 * 1024); // 8192 f32
  float* a2 = a1 + 8192;                                       // 8192 f32

  hipMemsetAsync(a1, 0, 2 * 8192 * sizeof(float), stream);
  k1_seqfts<<<256, 256, 0, stream>>>(x, W1, wf1, wf2, FT, a1, a2);
  k2_attn<<<256, 512, 0, stream>>>(adj, FT, a1, a2, b1, b2, out);
}